// Round 5
// baseline (49023.425 us; speedup 1.0000x reference)
//
#include <hip/hip_runtime.h>

#define T_STEPS 8192
#define HDIM 1024
#define NL0 64            // layer-0 workgroups
#define NL1 128           // layer-1 workgroups
#define NWG (NL0 + NL1)   // compute WGs (+1 monitor)
#define RMASK 63          // ring depth 64
#define PVALVE 300000L    // valve iterations
typedef float v2f __attribute__((ext_vector_type(2)));

// ---------- helpers ----------
__device__ __forceinline__ float wred(float v) {
#pragma unroll
    for (int s = 32; s >= 1; s >>= 1) v += __shfl_xor(v, s, 64);
    return v;
}
__device__ __forceinline__ int wred_min(int v) {
#pragma unroll
    for (int s = 32; s >= 1; s >>= 1) v = min(v, __shfl_xor(v, s, 64));
    return v;
}
__device__ __forceinline__ float sigm(float x) { return 1.0f / (1.0f + expf(-x)); }

__device__ __forceinline__ void st_coh_i32(int* p, int v) {
    asm volatile("global_store_dword %0, %1, off sc0 sc1" :: "v"(p), "v"(v) : "memory");
}
__device__ __forceinline__ void st_coh_f32(float* p, float v) {
    asm volatile("global_store_dword %0, %1, off sc0 sc1" :: "v"(p), "v"(v) : "memory");
}
__device__ __forceinline__ void st2f(float* p, float a, float b) {
    v2f v; v.x = a; v.y = b;
    asm volatile("global_store_dwordx2 %0, %1, off sc0 sc1" :: "v"(p), "v"(v) : "memory");
}
__device__ __forceinline__ int ld_coh_i32(const int* p) {
    int v;
    asm volatile("global_load_dword %0, %1, off sc0 sc1\n\ts_waitcnt vmcnt(0)"
                 : "=&v"(v) : "v"(p) : "memory");
    return v;
}
__device__ __forceinline__ v2f ld2f(const float* p) {
    v2f v;
    asm volatile("global_load_dwordx2 %0, %1, off sc0 sc1\n\ts_waitcnt vmcnt(0)"
                 : "=&v"(v) : "v"(p) : "memory");
    return v;
}
__device__ __forceinline__ void ld2f2(const float* p0, const float* p1, v2f& a, v2f& b) {
    asm volatile(
        "global_load_dwordx2 %0, %2, off sc0 sc1\n\t"
        "global_load_dwordx2 %1, %3, off sc0 sc1\n\t"
        "s_waitcnt vmcnt(0)"
        : "=&v"(a), "=&v"(b) : "v"(p0), "v"(p1) : "memory");
}
// three dense flag dwords: p[0], p[64], p[128]
__device__ __forceinline__ void ld3i(const int* p, int& a, int& b, int& c) {
    asm volatile(
        "global_load_dword %0, %3, off sc0 sc1\n\t"
        "global_load_dword %1, %3, off offset:256 sc0 sc1\n\t"
        "global_load_dword %2, %3, off offset:512 sc0 sc1\n\t"
        "s_waitcnt vmcnt(0)"
        : "=&v"(a), "=&v"(b), "=&v"(c) : "v"(p) : "memory");
}

// ---------- prologue: U = Wih0*Win, V = Wih0*bin + bih0 + bhh0, B1 = bih1 + bhh1 ----------
__global__ void lstm_prologue(const float* __restrict__ Wih0, const float* __restrict__ Win,
                              const float* __restrict__ bin, const float* __restrict__ bih0,
                              const float* __restrict__ bhh0, const float* __restrict__ bih1,
                              const float* __restrict__ bhh1,
                              float* __restrict__ U, float* __restrict__ V, float* __restrict__ B1) {
    const int wv = threadIdx.x >> 6, lane = threadIdx.x & 63;
    const int r = blockIdx.x * 4 + wv;
    const float* wp = Wih0 + (size_t)r * HDIM;
    float au = 0.f, av = 0.f;
#pragma unroll
    for (int j = 0; j < 16; ++j) {
        float wj = wp[lane + 64 * j];
        au += wj * Win[lane + 64 * j];
        av += wj * bin[lane + 64 * j];
    }
    au = wred(au);
    av = wred(av);
    if (lane == 0) {
        U[r] = au;
        V[r] = av + bih0[r] + bhh0[r];
        B1[r] = bih1[r] + bhh1[r];
    }
}

// ---------- persistent async LSTM: flags for wait, bulk sc-fetch for data ----------
// flags[0..63]=L0 steps done, flags[64..191]=L1 steps done, flags[256]=floor, flags[272]=abort
__global__ __launch_bounds__(512, 1) void lstm_persistent(
    const float* __restrict__ inputs, const float* __restrict__ Whh0,
    const float* __restrict__ Wih1, const float* __restrict__ Whh1,
    const float* __restrict__ Wout, int* flags, float* h0q, float* h1q,
    const float* __restrict__ U, const float* __restrict__ V, const float* __restrict__ B1,
    float* part) {
    __shared__ float kbuf[2048];
    __shared__ float ibuf[T_STEPS];
    __shared__ float osum[2][8];
    __shared__ int lds_ab;
    const int tid = threadIdx.x;
    const int wv = tid >> 6;
    const int lane = tid & 63;
    const int wg = blockIdx.x;
    int* flp = flags + 256;
    int* abp = flags + 272;

    if (wg == NWG) {
        // ---- monitor: floor = min over 192 flags ----
        if (tid >= 64) return;
        long it = 0;
        for (;;) {
            int a, b, c;
            ld3i(flags + lane, a, b, c);
            int m = wred_min(min(a, min(b, c)));
            if (lane == 0) st_coh_i32(flp, m);
            if (m >= T_STEPS) break;
            if ((++it & 63) == 0) {
                if (ld_coh_i32(abp)) break;
                if (it > PVALVE) { if (lane == 0) st_coh_i32(abp, 1); break; }
            }
        }
        return;
    }

    if (tid == 0) lds_ab = 0;

    if (wg < NL0) {
        // ---- layer 0: WG owns 16 h-elems; wave wv owns elems base_e, base_e+1 (8 gate rows).
        const int base_e = wg * 16 + wv * 2;
        float w[8][16];
        float uu[2][4], vv[2][4];
#pragma unroll
        for (int j = 0; j < 2; ++j)
#pragma unroll
            for (int g = 0; g < 4; ++g) {
                const int row = g * HDIM + base_e + j;
                const float* pw = Whh0 + (size_t)row * HDIM;
#pragma unroll
                for (int k = 0; k < 16; ++k) w[j * 4 + g][k] = pw[lane + 64 * k];
                uu[j][g] = U[row];
                vv[j][g] = V[row];
            }
#pragma unroll
        for (int k = 0; k < 16; ++k) ibuf[tid + 512 * k] = inputs[tid + 512 * k];
        __syncthreads();

        float c0 = 0.f, c1 = 0.f;
        for (int p = 0; p < T_STEPS; ++p) {
            // (a) wave0: lazy backpressure + flag poll; others wait at barrier
            if (wv == 0) {
                if (p >= 48 && (p & 7) == 0) {
                    long itf = 0;
                    for (;;) {
                        int fl = ld_coh_i32(flp);
                        if (fl >= p - 40) break;
                        if (ld_coh_i32(abp)) { lds_ab = 1; break; }
                        if (++itf > PVALVE) { st_coh_i32(abp, 1); lds_ab = 1; break; }
                    }
                }
                long it = 0;
                for (;;) {
                    int f = ld_coh_i32(flags + lane);   // 64 L0 flags, one per lane
                    if (__all(f >= p)) break;
                    if ((++it & 63) == 0) {
                        if (ld_coh_i32(abp) || it > PVALVE) {
                            st_coh_i32(abp, 1); lds_ab = 1; break;
                        }
                    }
                }
            }
            __syncthreads();
            if (lds_ab) break;
            // (b) bulk fetch h0[p-1] -> LDS
            {
                v2f hb = ld2f(h0q + (size_t)((p - 1) & RMASK) * HDIM + 2 * tid);
                kbuf[2 * tid] = hb.x;
                kbuf[2 * tid + 1] = hb.y;
            }
            __syncthreads();
            // (d) compute
            float hv[16];
#pragma unroll
            for (int j = 0; j < 16; ++j) hv[j] = kbuf[lane + 64 * j];
            float acc[8];
#pragma unroll
            for (int r = 0; r < 8; ++r) {
                float s = 0.f;
#pragma unroll
                for (int k = 0; k < 16; ++k) s += w[r][k] * hv[k];
                acc[r] = s;
            }
#pragma unroll
            for (int r = 0; r < 8; ++r) acc[r] = wred(acc[r]);
            const float st = ibuf[p];
            float gi = acc[0] + st * uu[0][0] + vv[0][0];
            float gf = acc[1] + st * uu[0][1] + vv[0][1];
            float gg = acc[2] + st * uu[0][2] + vv[0][2];
            float go = acc[3] + st * uu[0][3] + vv[0][3];
            float cn0 = sigm(gf) * c0 + sigm(gi) * tanhf(gg);
            float hn0 = sigm(go) * tanhf(cn0);
            c0 = cn0;
            gi = acc[4] + st * uu[1][0] + vv[1][0];
            gf = acc[5] + st * uu[1][1] + vv[1][1];
            gg = acc[6] + st * uu[1][2] + vv[1][2];
            go = acc[7] + st * uu[1][3] + vv[1][3];
            float cn1 = sigm(gf) * c1 + sigm(gi) * tanhf(gg);
            float hn1 = sigm(go) * tanhf(cn1);
            c1 = cn1;
            if (lane == 0)
                st2f(h0q + (size_t)(p & RMASK) * HDIM + base_e, hn0, hn1);
            asm volatile("s_waitcnt vmcnt(0)" ::: "memory");
            __syncthreads();
            // (e) publish: data of step p drained by ALL waves -> flag
            if (tid == 0) st_coh_i32(flags + wg, p + 1);
        }
    } else {
        // ---- layer 1: WG owns 8 h-elems; wave wv owns elem e (4 rows, K=2048). ----
        const int wgb = wg - NL0;
        const int e = wgb * 8 + wv;
        const int hl = lane & 31;
        const float* wsrc = (lane < 32) ? Wih1 : Whh1;
        float w[4][32];
        float bb[4];
#pragma unroll
        for (int g = 0; g < 4; ++g) {
            const int row = g * HDIM + e;
            const float* pw = wsrc + (size_t)row * HDIM;
#pragma unroll
            for (int k = 0; k < 32; ++k) w[g][k] = pw[hl + 32 * k];
            bb[g] = B1[row];
        }
        const float woute = Wout[e];
        __syncthreads();

        float c1s = 0.f;
        for (int t = 0; t < T_STEPS; ++t) {
            if (wv == 0) {
                if (t >= 48 && (t & 7) == 0) {
                    long itf = 0;
                    for (;;) {
                        int fl = ld_coh_i32(flp);
                        if (fl >= t - 40) break;
                        if (ld_coh_i32(abp)) { lds_ab = 1; break; }
                        if (++itf > PVALVE) { st_coh_i32(abp, 1); lds_ab = 1; break; }
                    }
                }
                long it = 0;
                for (;;) {
                    int f0, f1a, f1b;
                    ld3i(flags + lane, f0, f1a, f1b);   // L0[lane], L1[lane], L1[lane+64]
                    if (__all(f0 >= t + 1 && f1a >= t && f1b >= t)) break;
                    if ((++it & 63) == 0) {
                        if (ld_coh_i32(abp) || it > PVALVE) {
                            st_coh_i32(abp, 1); lds_ab = 1; break;
                        }
                    }
                }
            }
            __syncthreads();
            if (lds_ab) break;
            // bulk fetch h0[t] and h1[t-1] -> LDS
            {
                v2f a, b;
                ld2f2(h0q + (size_t)(t & RMASK) * HDIM + 2 * tid,
                      h1q + (size_t)((t - 1) & RMASK) * HDIM + 2 * tid, a, b);
                kbuf[2 * tid] = a.x;
                kbuf[2 * tid + 1] = a.y;
                kbuf[1024 + 2 * tid] = b.x;
                kbuf[1024 + 2 * tid + 1] = b.y;
            }
            __syncthreads();
            if (tid == 0 && t >= 1) {   // deferred output partial for t-1 (off critical path)
                const int q = (t - 1) & 1;
                float s = osum[q][0] + osum[q][1] + osum[q][2] + osum[q][3] +
                          osum[q][4] + osum[q][5] + osum[q][6] + osum[q][7];
                part[(size_t)(t - 1) * 128 + wgb] = s;
            }
            const int koff = (lane < 32) ? 0 : 1024;
            float hv[32];
#pragma unroll
            for (int j = 0; j < 32; ++j) hv[j] = kbuf[koff + hl + 32 * j];
            float acc[4];
#pragma unroll
            for (int g = 0; g < 4; ++g) {
                float s = 0.f;
#pragma unroll
                for (int k = 0; k < 32; ++k) s += w[g][k] * hv[k];
                acc[g] = s;
            }
#pragma unroll
            for (int g = 0; g < 4; ++g) acc[g] = wred(acc[g]);
            const float gi = acc[0] + bb[0];
            const float gf = acc[1] + bb[1];
            const float gg = acc[2] + bb[2];
            const float go = acc[3] + bb[3];
            const float cn = sigm(gf) * c1s + sigm(gi) * tanhf(gg);
            const float hn = sigm(go) * tanhf(cn);
            c1s = cn;
            if (lane == 0) {
                st_coh_f32(h1q + (size_t)(t & RMASK) * HDIM + e, hn);
                osum[t & 1][wv] = woute * hn;
            }
            asm volatile("s_waitcnt vmcnt(0)" ::: "memory");
            __syncthreads();
            if (tid == 0) st_coh_i32(flags + wg, t + 1);
        }
        if (tid == 0) {
            const int q = (T_STEPS - 1) & 1;
            float s = osum[q][0] + osum[q][1] + osum[q][2] + osum[q][3] +
                      osum[q][4] + osum[q][5] + osum[q][6] + osum[q][7];
            part[(size_t)(T_STEPS - 1) * 128 + wgb] = s;
        }
    }
}

// ---------- output projection: out[t] = b_out + sum_wb part[t][wb] ----------
__global__ void lstm_finalize(const float* __restrict__ part, const float* __restrict__ bout,
                              float* __restrict__ out) {
    const int t = blockIdx.x * 256 + threadIdx.x;
    if (t < T_STEPS) {
        const float4* p4 = (const float4*)(part + (size_t)t * 128);
        float s = bout[0];
#pragma unroll
        for (int i = 0; i < 32; ++i) {
            float4 v = p4[i];
            s += v.x + v.y + v.z + v.w;
        }
        out[t] = s;
    }
}

extern "C" void kernel_launch(void* const* d_in, const int* in_sizes, int n_in,
                              void* d_out, int out_size, void* d_ws, size_t ws_size,
                              hipStream_t stream) {
    const float* inputs = (const float*)d_in[0];
    const float* Win  = (const float*)d_in[1];
    const float* bin  = (const float*)d_in[2];
    const float* Wih0 = (const float*)d_in[3];
    const float* Whh0 = (const float*)d_in[4];
    const float* bih0 = (const float*)d_in[5];
    const float* bhh0 = (const float*)d_in[6];
    const float* Wih1 = (const float*)d_in[7];
    const float* Whh1 = (const float*)d_in[8];
    const float* bih1 = (const float*)d_in[9];
    const float* bhh1 = (const float*)d_in[10];
    const float* Wout = (const float*)d_in[11];
    const float* bout = (const float*)d_in[12];

    char* ws = (char*)d_ws;
    int*   flags = (int*)ws;                      // 4KB: [0..191] flags, [256] floor, [272] abort
    float* h0q   = (float*)(ws + 4096);           // 64*1024*4 = 256KB (ends 266240)
    float* h1q   = (float*)(ws + 266240);         // 256KB (ends 528384)
    float* U     = (float*)(ws + 528384);         // 16KB
    float* V     = (float*)(ws + 544768);         // 16KB
    float* B1    = (float*)(ws + 561152);         // 16KB (ends 577536)
    float* part  = (float*)(ws + 577536);         // 8192*128*4 = 4MB (ends 4771840)

    if (ws_size < (size_t)4771840) return;

    hipMemsetAsync(ws, 0, 528384, stream);        // flags + floor + abort + both rings

    lstm_prologue<<<1024, 256, 0, stream>>>(Wih0, Win, bin, bih0, bhh0, bih1, bhh1, U, V, B1);
    lstm_persistent<<<NWG + 1, 512, 0, stream>>>(inputs, Whh0, Wih1, Whh1, Wout,
                                                 flags, h0q, h1q, U, V, B1, part);
    lstm_finalize<<<(T_STEPS + 255) / 256, 256, 0, stream>>>(part, bout, (float*)d_out);
}